// Round 11
// baseline (48193.518 us; speedup 1.0000x reference)
//
#include <hip/hip_runtime.h>
#include <stdint.h>

typedef float f32x4 __attribute__((ext_vector_type(4)));

#define SLEN 8192
#define NBLK 256

// IC rings: h1 at byte 0, h0 at 16384. Each: 2 parities x 256 CUs x 2 chunks x 16B.
// CU b, chunk0 = {h[4b],h[4b+1],h[4b+2],tag}, chunk1 = {h[4b+3], 0, 0, tag}
// Leaders (blk<8) relay ring -> per-XCD mailbox (sc0-only, XCD-local L2).
#define RING_PAR 8192
#define H0_OFF   16384
#define MB_OFF   32768
#define MB_STRIDE 32768            // per XCD: 2 par x (h1 8KB @0 + h0 8KB @8192)
#define WS_BYTES (MB_OFF + 8 * MB_STRIDE)   // 294912

#define LDS_REL(p, v) __hip_atomic_store((p), (v), __ATOMIC_RELEASE, __HIP_MEMORY_SCOPE_WORKGROUP)
#define LDS_ACQ(p)    __hip_atomic_load((p), __ATOMIC_ACQUIRE, __HIP_MEMORY_SCOPE_WORKGROUP)

static __device__ __forceinline__ void st_chunk(void* addr, f32x4 v) {
  asm volatile("global_store_dwordx4 %0, %1, off sc0 sc1"
               :: "v"(addr), "v"(v) : "memory");
}
static __device__ __forceinline__ void ld32(const void* a, f32x4& v0, f32x4& v1) {
  asm volatile("global_load_dwordx4 %0, %2, off sc0 sc1\n\t"
               "global_load_dwordx4 %1, %2, off offset:16 sc0 sc1\n\t"
               "s_waitcnt vmcnt(0)"
               : "=v"(v0), "=v"(v1) : "v"(a) : "memory");
}
static __device__ __forceinline__ void poll32(const void* a, unsigned tag,
                                              f32x4& v0, f32x4& v1) {
  ld32(a, v0, v1);
  while (__float_as_uint(v0.w) != tag || __float_as_uint(v1.w) != tag) {
    __builtin_amdgcn_s_sleep(2);
    ld32(a, v0, v1);
  }
}
// leader poll: no sleep (tight discovery cadence; only 8 CUs do this)
static __device__ __forceinline__ void poll32_ns(const void* a, unsigned tag,
                                                 f32x4& v0, f32x4& v1) {
  ld32(a, v0, v1);
  while (__float_as_uint(v0.w) != tag || __float_as_uint(v1.w) != tag) {
    ld32(a, v0, v1);
  }
}
// XCD-local mailbox ops: sc0 only (bypass L1, hit the XCD-shared L2)
static __device__ __forceinline__ void ld32_mb(const void* a, f32x4& v0, f32x4& v1) {
  asm volatile("global_load_dwordx4 %0, %2, off sc0\n\t"
               "global_load_dwordx4 %1, %2, off offset:16 sc0\n\t"
               "s_waitcnt vmcnt(0)"
               : "=v"(v0), "=v"(v1) : "v"(a) : "memory");
}
static __device__ __forceinline__ void st_mb(void* a, f32x4 v0, f32x4 v1) {
  asm volatile("global_store_dwordx4 %0, %1, off sc0\n\t"
               "global_store_dwordx4 %0, %2, off offset:16 sc0"
               :: "v"(a), "v"(v0), "v"(v1) : "memory");
}
// follower poll: mailbox first (no sleep, local L2), IC fallback after 64 tries;
// 4 consecutive fallbacks latch the mailbox dead (wrong-XCD-mapping rescue).
static __device__ __forceinline__ void poll_rly(const void* mb, const void* ic,
                                                unsigned tag, f32x4& v0, f32x4& v1,
                                                int& dead) {
  if (dead < 4) {
    ld32_mb(mb, v0, v1);
    int tries = 0;
    while (__float_as_uint(v0.w) != tag || __float_as_uint(v1.w) != tag) {
      if (++tries >= 64) break;
      ld32_mb(mb, v0, v1);
    }
    if (__float_as_uint(v0.w) == tag && __float_as_uint(v1.w) == tag) {
      dead = 0;
      return;
    }
    ++dead;
  }
  poll32(ic, tag, v0, v1);
}

static __device__ __forceinline__ float sigm(float v) { return 1.f / (1.f + expf(-v)); }
static __device__ __forceinline__ float tanh_f(float v) {
  float e = expf(-2.f * fabsf(v));
  return copysignf((1.f - e) / (1.f + e), v);
}
static __device__ __forceinline__ float lstm_h(float a0, float a1, float a2, float a3,
                                               float& c) {
  float ii = sigm(a0), ff = sigm(a1), gg = tanh_f(a2), oo = sigm(a3);
  c = ff * c + ii * gg;
  return oo * tanh_f(c);
}
// wave64 sum via DPP; total lands in lane 63
static __device__ __forceinline__ float dpp_red(float x) {
  x += __int_as_float(__builtin_amdgcn_update_dpp(0, __float_as_int(x), 0x111, 0xf, 0xf, true));
  x += __int_as_float(__builtin_amdgcn_update_dpp(0, __float_as_int(x), 0x112, 0xf, 0xf, true));
  x += __int_as_float(__builtin_amdgcn_update_dpp(0, __float_as_int(x), 0x114, 0xf, 0xf, true));
  x += __int_as_float(__builtin_amdgcn_update_dpp(0, __float_as_int(x), 0x118, 0xf, 0xf, true));
  x += __int_as_float(__builtin_amdgcn_update_dpp(0, __float_as_int(x), 0x142, 0xa, 0xf, true));
  x += __int_as_float(__builtin_amdgcn_update_dpp(0, __float_as_int(x), 0x143, 0xc, 0xf, true));
  return x;
}
static __device__ __forceinline__ float dot4(f32x4 a, f32x4 b) {
  return a.x * b.x + a.y * b.y + a.z * b.z + a.w * b.w;
}
// padded hidden-vector layout: chunk stride 20 floats (80B) -> conflict-free b128
static __device__ __forceinline__ int lds_idx4(int j) { return (j >> 2) * 20 + (j & 3) * 4; }

__global__ __launch_bounds__(512, 2) void lstm_fused(
    const float* __restrict__ x, const int* __restrict__ mask,
    const float* __restrict__ feat, const int* __restrict__ tfp,
    const float* __restrict__ w_ih0, const float* __restrict__ w_hh0,
    const float* __restrict__ b_ih0, const float* __restrict__ b_hh0,
    const float* __restrict__ w_ih1, const float* __restrict__ w_hh1,
    const float* __restrict__ b_ih1, const float* __restrict__ b_hh1,
    const float* __restrict__ w_ffn, const float* __restrict__ b_ffn,
    float* __restrict__ out, char* __restrict__ ws)
{
  char* h1ring = ws;
  char* h0ring = ws + H0_OFF;
  const int tid = threadIdx.x, lane = tid & 63, wv = tid >> 6;
  const int blk = blockIdx.x;
  const int u = wv & 3;
  const int m = blk * 4 + u;            // owned hidden unit (both layers)
  const bool L1w = wv < 4;              // waves 0-3: layer-1 ; waves 4-7: layer-0
  const bool leader = blk < 8;          // one relay block per XCD (round-robin map)
  char* mbx = ws + MB_OFF + (blk & 7) * MB_STRIDE;

  __shared__ __align__(16) float wh1_lds[16 * 1280];   // 80 KB
  __shared__ __align__(16) float lh0[2][1280];         // parity-buffered h0
  __shared__ __align__(16) float lh1[2][1280];         // parity-buffered h1
  __shared__ float g1hv[4], g0hv[4];
  __shared__ unsigned g1ht[4], g0ht[4];
  __shared__ float ypv[2][4];                          // per-L1-wave y partials
  __shared__ unsigned ypt[2][4];

  // ---- per-role weight matrix in VGPRs ----
  f32x4 W[4][4];
  {
    const float* Wsrc = L1w ? w_ih1 : w_hh0;
#pragma unroll
    for (int g = 0; g < 4; ++g) {
      const f32x4* s = reinterpret_cast<const f32x4*>(
          Wsrc + (size_t)(1024 * g + m) * 1024 + lane * 16);
#pragma unroll
      for (int q = 0; q < 4; ++q) W[g][q] = s[q];
    }
  }
  float wA[4], wB[4];
#pragma unroll
  for (int g = 0; g < 4; ++g) {
    const int r = 1024 * g + m;
    if (L1w) {
      wA[g] = (lane == 16) ? (b_ih1[r] + b_hh1[r]) : 0.f;
      wB[g] = 0.f;
    } else {
      wA[g] = (lane < 16) ? w_ih0[r * 16 + lane]
            : (lane == 16 ? (b_ih0[r] + b_hh0[r]) : 0.f);
      wB[g] = w_ih0[r * 16];
    }
  }
  const f32x4 wffn4 = L1w ? reinterpret_cast<const f32x4*>(w_ffn)[tid & 255]
                          : f32x4{0.f, 0.f, 0.f, 0.f};
  const float bf = b_ffn[0];
  float cc = 0.f;
  int fb0 = 0, fb1 = 0;                 // mailbox dead-latch counters

  if (tid < 4) {
    g1ht[tid] = 0xFFFFFFFFu; g0ht[tid] = 0xFFFFFFFFu;
    ypt[0][tid] = 0xFFFFFFFFu; ypt[1][tid] = 0xFFFFFFFFu;
  }
  // ---- stage w_hh1 into LDS (pad-20 layout) ----
  for (int ch = tid; ch < 1024; ch += 512) {
    const int r = ch >> 6, kc = ch & 63;
    const int grow = 1024 * (r & 3) + blk * 4 + (r >> 2);
    const f32x4* src = reinterpret_cast<const f32x4*>(
        w_hh1 + (size_t)grow * 1024 + kc * 16);
    f32x4* dst = reinterpret_cast<f32x4*>(&wh1_lds[r * 1280 + kc * 20]);
    dst[0] = src[0]; dst[1] = src[1]; dst[2] = src[2]; dst[3] = src[3];
  }
  __syncthreads();

  const bool tf1 = (*tfp) >= 1;
  float acc0[4];

  for (int t = 0; t < SLEN; ++t) {
    const bool use_x = (t == 0) || (tf1 && mask[t] != 0);
    const bool needy = (t > 0) && !use_x;

    if (L1w) {
      // ===== P1: compute h1[t-1], flag it =====
      if (t > 0) {
        __builtin_amdgcn_s_setprio(1);
        float a[4];
        const f32x4* h0v = reinterpret_cast<const f32x4*>(&lh0[(t - 1) & 1][lane * 20]);
        f32x4 p0 = h0v[0], p1 = h0v[1], p2 = h0v[2], p3 = h0v[3];
#pragma unroll
        for (int g = 0; g < 4; ++g)
          a[g] = wA[g] + dot4(W[g][0], p0) + dot4(W[g][1], p1) +
                          dot4(W[g][2], p2) + dot4(W[g][3], p3);
        if (t > 1) {
          const f32x4* h1v = reinterpret_cast<const f32x4*>(&lh1[t & 1][lane * 20]);
          f32x4 q0 = h1v[0], q1 = h1v[1], q2 = h1v[2], q3 = h1v[3];
#pragma unroll
          for (int g = 0; g < 4; ++g) {
            const f32x4* wb = reinterpret_cast<const f32x4*>(
                &wh1_lds[(u * 4 + g) * 1280 + lane * 20]);
            a[g] += dot4(wb[0], q0) + dot4(wb[1], q1) +
                    dot4(wb[2], q2) + dot4(wb[3], q3);
          }
        }
#pragma unroll
        for (int g = 0; g < 4; ++g) a[g] = dpp_red(a[g]);
        if (lane == 63) {
          float h = lstm_h(a[0], a[1], a[2], a[3], cc);
          g1hv[u] = h;
          LDS_REL(&g1ht[u], (unsigned)(t - 1));
        }
        __builtin_amdgcn_s_setprio(0);
      }
      // blk0: deferred out[t-2] (step t-1 used x; ypv barrier-ordered by E)
      if (blk == 0 && wv == 3 && lane == 0 && t >= 2 && (tf1 && mask[t - 1] != 0)) {
        const int sl = (t - 2) & 1;
        out[t - 2] = ((ypv[sl][0] + ypv[sl][1]) + (ypv[sl][2] + ypv[sl][3])) + bf;
      }
      // ===== stage h1[t-1] ; wave0 funnels h0[t] (order depends on step type) =====
      const bool fun_first = (wv == 0) && !needy;
      if (fun_first && lane < 2) {
        while (LDS_ACQ(&g0ht[0]) != (unsigned)t) {}
        while (LDS_ACQ(&g0ht[1]) != (unsigned)t) {}
        while (LDS_ACQ(&g0ht[2]) != (unsigned)t) {}
        while (LDS_ACQ(&g0ht[3]) != (unsigned)t) {}
        f32x4 v;
        if (lane == 0) { v.x = g0hv[0]; v.y = g0hv[1]; v.z = g0hv[2]; }
        else           { v.x = g0hv[3]; v.y = 0.f; v.z = 0.f; }
        v.w = __uint_as_float((unsigned)t);
        st_chunk(h0ring + (t & 1) * RING_PAR + blk * 32 + lane * 16, v);
      }
      if (t > 0) {
        const char* ic = h1ring + ((t - 1) & 1) * RING_PAR + tid * 32;
        char* mb = mbx + ((t - 1) & 1) * 16384 + tid * 32;
        f32x4 v0, v1;
        if (leader) { poll32_ns(ic, (unsigned)(t - 1), v0, v1); st_mb(mb, v0, v1); }
        else        { poll_rly(mb, ic, (unsigned)(t - 1), v0, v1, fb1); }
        f32x4 h4; h4.x = v0.x; h4.y = v0.y; h4.z = v0.z; h4.w = v1.x;
        *reinterpret_cast<f32x4*>(&lh1[(t - 1) & 1][lds_idx4(tid)]) = h4;
        float p = dpp_red(dot4(wffn4, h4));
        if (lane == 63) {
          ypv[(t - 1) & 1][u] = p;
          LDS_REL(&ypt[(t - 1) & 1][u], (unsigned)(t - 1));
        }
      }
      if (!fun_first && wv == 0 && lane < 2) {   // needy: stage first, then funnel
        while (LDS_ACQ(&g0ht[0]) != (unsigned)t) {}
        while (LDS_ACQ(&g0ht[1]) != (unsigned)t) {}
        while (LDS_ACQ(&g0ht[2]) != (unsigned)t) {}
        while (LDS_ACQ(&g0ht[3]) != (unsigned)t) {}
        f32x4 v;
        if (lane == 0) { v.x = g0hv[0]; v.y = g0hv[1]; v.z = g0hv[2]; }
        else           { v.x = g0hv[3]; v.y = 0.f; v.z = 0.f; }
        v.w = __uint_as_float((unsigned)t);
        st_chunk(h0ring + (t & 1) * RING_PAR + blk * 32 + lane * 16, v);
      }
    } else {
      // ===== P1: L0 matvec =====
      float base = (lane == 0) ? (use_x ? x[t] : 0.f)
                 : (lane < 16) ? feat[t * 15 + lane - 1]
                 : (lane == 16) ? 1.f : 0.f;
      __builtin_amdgcn_s_setprio(1);
#pragma unroll
      for (int g = 0; g < 4; ++g) acc0[g] = wA[g] * base;
      if (t > 0) {
        const f32x4* h0v = reinterpret_cast<const f32x4*>(&lh0[(t - 1) & 1][lane * 20]);
        f32x4 p0 = h0v[0], p1 = h0v[1], p2 = h0v[2], p3 = h0v[3];
#pragma unroll
        for (int g = 0; g < 4; ++g)
          acc0[g] += dot4(W[g][0], p0) + dot4(W[g][1], p1) +
                     dot4(W[g][2], p2) + dot4(W[g][3], p3);
      }
#pragma unroll
      for (int g = 0; g < 4; ++g) acc0[g] = dpp_red(acc0[g]);
      __builtin_amdgcn_s_setprio(0);
      // wave4: h1 funnel (publish before any y wait - y depends on it)
      if (wv == 4 && lane < 2 && t > 0) {
        while (LDS_ACQ(&g1ht[0]) != (unsigned)(t - 1)) {}
        while (LDS_ACQ(&g1ht[1]) != (unsigned)(t - 1)) {}
        while (LDS_ACQ(&g1ht[2]) != (unsigned)(t - 1)) {}
        while (LDS_ACQ(&g1ht[3]) != (unsigned)(t - 1)) {}
        f32x4 v;
        if (lane == 0) { v.x = g1hv[0]; v.y = g1hv[1]; v.z = g1hv[2]; }
        else           { v.x = g1hv[3]; v.y = 0.f; v.z = 0.f; }
        v.w = __uint_as_float((unsigned)(t - 1));
        st_chunk(h1ring + ((t - 1) & 1) * RING_PAR + blk * 32 + lane * 16, v);
      }
      // gates (+ y wait on needy), flag h0[t]
      if (lane == 63) {
        if (needy) {
          const int sl = (t - 1) & 1;
          while (LDS_ACQ(&ypt[sl][0]) != (unsigned)(t - 1)) {}
          while (LDS_ACQ(&ypt[sl][1]) != (unsigned)(t - 1)) {}
          while (LDS_ACQ(&ypt[sl][2]) != (unsigned)(t - 1)) {}
          while (LDS_ACQ(&ypt[sl][3]) != (unsigned)(t - 1)) {}
          float yy = ((ypv[sl][0] + ypv[sl][1]) + (ypv[sl][2] + ypv[sl][3])) + bf;
          if (blk == 0 && wv == 4) out[t - 1] = yy;
#pragma unroll
          for (int g = 0; g < 4; ++g) acc0[g] += yy * wB[g];
        }
        float h = lstm_h(acc0[0], acc0[1], acc0[2], acc0[3], cc);
        g0hv[u] = h;
        LDS_REL(&g0ht[u], (unsigned)t);
      }
      // stage h0[t]
      const int j = tid - 256;
      const char* ic = h0ring + (t & 1) * RING_PAR + j * 32;
      char* mb = mbx + (t & 1) * 16384 + 8192 + j * 32;
      f32x4 v0, v1;
      if (leader) { poll32_ns(ic, (unsigned)t, v0, v1); st_mb(mb, v0, v1); }
      else        { poll_rly(mb, ic, (unsigned)t, v0, v1, fb0); }
      f32x4 h4; h4.x = v0.x; h4.y = v0.y; h4.z = v0.z; h4.w = v1.x;
      *reinterpret_cast<f32x4*>(&lh0[t & 1][lds_idx4(j)]) = h4;
    }
    __syncthreads();  // E (the only block barrier per step)
  }

  // ===== tail: deferred out[SLEN-2], h1[SLEN-1], out[SLEN-1] =====
  if (blk == 0 && wv == 3 && lane == 0 && (tf1 && mask[SLEN - 1] != 0)) {
    const int sl = (SLEN - 2) & 1;
    out[SLEN - 2] = ((ypv[sl][0] + ypv[sl][1]) + (ypv[sl][2] + ypv[sl][3])) + bf;
  }
  if (L1w) {
    float a[4];
    const f32x4* h0v = reinterpret_cast<const f32x4*>(&lh0[(SLEN - 1) & 1][lane * 20]);
    f32x4 p0 = h0v[0], p1 = h0v[1], p2 = h0v[2], p3 = h0v[3];
#pragma unroll
    for (int g = 0; g < 4; ++g)
      a[g] = wA[g] + dot4(W[g][0], p0) + dot4(W[g][1], p1) +
                      dot4(W[g][2], p2) + dot4(W[g][3], p3);
    {
      const f32x4* h1v = reinterpret_cast<const f32x4*>(&lh1[(SLEN - 2) & 1][lane * 20]);
      f32x4 q0 = h1v[0], q1 = h1v[1], q2 = h1v[2], q3 = h1v[3];
#pragma unroll
      for (int g = 0; g < 4; ++g) {
        const f32x4* wb = reinterpret_cast<const f32x4*>(
            &wh1_lds[(u * 4 + g) * 1280 + lane * 20]);
        a[g] += dot4(wb[0], q0) + dot4(wb[1], q1) +
                dot4(wb[2], q2) + dot4(wb[3], q3);
      }
    }
#pragma unroll
    for (int g = 0; g < 4; ++g) a[g] = dpp_red(a[g]);
    if (lane == 63) {
      float h = lstm_h(a[0], a[1], a[2], a[3], cc);
      g1hv[u] = h;
      LDS_REL(&g1ht[u], (unsigned)(SLEN - 1));
    }
  } else if (wv == 4 && lane < 2) {
    while (LDS_ACQ(&g1ht[0]) != (unsigned)(SLEN - 1)) {}
    while (LDS_ACQ(&g1ht[1]) != (unsigned)(SLEN - 1)) {}
    while (LDS_ACQ(&g1ht[2]) != (unsigned)(SLEN - 1)) {}
    while (LDS_ACQ(&g1ht[3]) != (unsigned)(SLEN - 1)) {}
    f32x4 v;
    if (lane == 0) { v.x = g1hv[0]; v.y = g1hv[1]; v.z = g1hv[2]; }
    else           { v.x = g1hv[3]; v.y = 0.f; v.z = 0.f; }
    v.w = __uint_as_float((unsigned)(SLEN - 1));
    st_chunk(h1ring + ((SLEN - 1) & 1) * RING_PAR + blk * 32 + lane * 16, v);
    asm volatile("s_waitcnt vmcnt(0)" ::: "memory");
  }
  if (blk == 0 && L1w) {
    f32x4 v0, v1;
    poll32(h1ring + ((SLEN - 1) & 1) * RING_PAR + tid * 32, (unsigned)(SLEN - 1), v0, v1);
    f32x4 h4; h4.x = v0.x; h4.y = v0.y; h4.z = v0.z; h4.w = v1.x;
    float p = dpp_red(dot4(wffn4, h4));
    if (lane == 63) {
      ypv[(SLEN - 1) & 1][u] = p;
      LDS_REL(&ypt[(SLEN - 1) & 1][u], (unsigned)(SLEN - 1));
    }
  }
  if (blk == 0 && wv == 3 && lane == 1) {
    const int sl = (SLEN - 1) & 1;
    while (LDS_ACQ(&ypt[sl][0]) != (unsigned)(SLEN - 1)) {}
    while (LDS_ACQ(&ypt[sl][1]) != (unsigned)(SLEN - 1)) {}
    while (LDS_ACQ(&ypt[sl][2]) != (unsigned)(SLEN - 1)) {}
    while (LDS_ACQ(&ypt[sl][3]) != (unsigned)(SLEN - 1)) {}
    out[SLEN - 1] = ((ypv[sl][0] + ypv[sl][1]) + (ypv[sl][2] + ypv[sl][3])) + bf;
  }
}

extern "C" void kernel_launch(void* const* d_in, const int* in_sizes, int n_in,
                              void* d_out, int out_size, void* d_ws, size_t ws_size,
                              hipStream_t stream) {
  (void)in_sizes; (void)n_in; (void)out_size; (void)ws_size;
  const float* x      = (const float*)d_in[0];
  const int*   mask   = (const int*)  d_in[1];
  const float* feat   = (const float*)d_in[2];
  const int*   tfp    = (const int*)  d_in[3];
  const float* w_ih0  = (const float*)d_in[4];
  const float* w_hh0  = (const float*)d_in[5];
  const float* b_ih0  = (const float*)d_in[6];
  const float* b_hh0  = (const float*)d_in[7];
  const float* w_ih1  = (const float*)d_in[8];
  const float* w_hh1  = (const float*)d_in[9];
  const float* b_ih1  = (const float*)d_in[10];
  const float* b_hh1  = (const float*)d_in[11];
  const float* w_ffn  = (const float*)d_in[12];
  const float* b_ffn  = (const float*)d_in[13];
  float* out = (float*)d_out;
  char*  ws  = (char*)d_ws;

  // invalidate all ring + mailbox tags (0xFFFFFFFF never equals a step index)
  hipMemsetAsync(d_ws, 0xFF, (size_t)WS_BYTES, stream);

  lstm_fused<<<dim3(NBLK), dim3(512), 0, stream>>>(
      x, mask, feat, tfp, w_ih0, w_hh0, b_ih0, b_hh0,
      w_ih1, w_hh1, b_ih1, b_hh1, w_ffn, b_ffn, out, ws);
}